// Round 3
// baseline (445.489 us; speedup 1.0000x reference)
//
#include <hip/hip_runtime.h>

typedef __bf16 bf16_t;
typedef bf16_t bf16x8 __attribute__((ext_vector_type(8)));
typedef float  floatx4 __attribute__((ext_vector_type(4)));
typedef unsigned int uint;

constexpr int Mdim = 2048;
constexpr int Kdim = 4096;
constexpr int Ndim = 11008;
constexpr int NPK  = Ndim / 8;     // 1376 packed words per k-row
constexpr int BM = 128, BN = 128, BK = 64;
constexpr int SQ = 68;             // qbuf stride in words (272 B, 16B-aligned, bank-staggered)

__global__ void xcast_kernel(const float* __restrict__ x, bf16_t* __restrict__ xb)
{
    const int i = (blockIdx.x * 256 + threadIdx.x) * 8;
    const float4 a = *(const float4*)(x + i);
    const float4 b = *(const float4*)(x + i + 4);
    bf16x8 v;
    v[0] = (bf16_t)a.x; v[1] = (bf16_t)a.y; v[2] = (bf16_t)a.z; v[3] = (bf16_t)a.w;
    v[4] = (bf16_t)b.x; v[5] = (bf16_t)b.y; v[6] = (bf16_t)b.z; v[7] = (bf16_t)b.w;
    *(bf16x8*)(xb + i) = v;
}

__device__ __forceinline__ void gload_lds16(const bf16_t* g, bf16_t* l)
{
    __builtin_amdgcn_global_load_lds((const __attribute__((address_space(1))) void*)g,
                                     (__attribute__((address_space(3))) void*)l, 16, 0, 0);
}

template <bool PRE>
__global__ __launch_bounds__(256, 3)
void qgemm_kernel(const float* __restrict__ x,
                  const bf16_t* __restrict__ xb,
                  const uint* __restrict__ qweight,
                  const uint* __restrict__ qzeros,
                  const float* __restrict__ scales,
                  const float* __restrict__ bias,
                  float* __restrict__ out)
{
    // As: 128 rows x 64 k, UNPADDED (row = 128 B), 16B-granule XOR swizzle:
    // LDS slot (row, gs) holds global granule (row, gs ^ (row&7)).
    __shared__ bf16_t As[BM * BK];     // 16384 B
    __shared__ uint   qbuf[16 * SQ];   //  4352 B  [c][k] transposed packed words

    const int t  = threadIdx.x;
    const int m0 = blockIdx.y * BM;
    const int n0 = blockIdx.x * BN;
    const int c0 = n0 >> 3;

    const int wave = t >> 6;
    const int lane = t & 63;
    const int quad = lane >> 4;
    const int l16  = lane & 15;
    const int mw = (wave >> 1) * 64;
    const int nw = (wave & 1) * 64;

    // A staging: wave covers 8 rows/instr; lane -> (row=+lane>>3, slot gs=lane&7),
    // fetches global granule gs ^ (row&7) = gs ^ r8 (row%8 == r8 here).
    const int r8   = lane >> 3;
    const int gs   = lane & 7;
    const int gcol = gs ^ r8;

    // qbuf staging: thread t loads dwordx4 at row k=t>>2, cols (t&3)*4..+3; stores transposed.
    const int qk  = t >> 2;
    const int qc4 = (t & 3) * 4;

    // dequant / fragment constants (per lane)
    const int jsh = (l16 & 7) * 4;
    const int e3  = l16 & 7;
    int qrowoff[4];                    // qbuf word offset per n-tile
#pragma unroll
    for (int nt = 0; nt < 4; ++nt)
        qrowoff[nt] = ((nw >> 3) + nt * 2 + (l16 >> 3)) * SQ;
    int arowoff[4];                    // As elem offset per m-tile
#pragma unroll
    for (int mt = 0; mt < 4; ++mt)
        arowoff[mt] = (mw + mt * 16 + l16) * BK;
    int aslot[2], qoff[2];
#pragma unroll
    for (int s2 = 0; s2 < 2; ++s2) {
        aslot[s2] = (((s2 * 4 + quad) ^ e3) * 8);   // swizzled granule -> elem offset
        qoff[s2]  = s2 * 32 + quad * 8;
    }

    floatx4 acc[4][4];
#pragma unroll
    for (int i = 0; i < 4; ++i)
#pragma unroll
        for (int j = 0; j < 4; ++j)
            acc[i][j] = (floatx4){0.f, 0.f, 0.f, 0.f};

    for (int g = 0; g < 32; ++g) {
        // per-group scale / zero*scale per n-tile
        float sN[4], zsN[4];
#pragma unroll
        for (int nt = 0; nt < 4; ++nt) {
            const int col = n0 + nw + nt * 16 + l16;
            const float sv = scales[(size_t)g * Ndim + col];
            const uint  zw = qzeros[(size_t)g * NPK + (col >> 3)];
            sN[nt]  = sv;
            zsN[nt] = (float)((zw >> jsh) & 15u) * sv;
        }

#pragma unroll 1
        for (int half = 0; half < 2; ++half) {
            const int k0 = g * 128 + half * 64;

            // ---- stage A (global_load_lds, swizzled) ----
            if (PRE) {
#pragma unroll
                for (int p = 0; p < 4; ++p) {
                    const bf16_t* gp = xb + (size_t)(m0 + p * 32 + wave * 8 + r8) * Kdim
                                          + k0 + gcol * 8;
                    gload_lds16(gp, &As[(p * 32 + wave * 8) * BK]);
                }
            } else {
#pragma unroll
                for (int p = 0; p < 4; ++p) {
                    const int row = p * 32 + wave * 8 + r8;
                    const float* src = x + (size_t)(m0 + row) * Kdim + k0 + gcol * 8;
                    const float4 a = *(const float4*)src;
                    const float4 b = *(const float4*)(src + 4);
                    bf16x8 v;
                    v[0] = (bf16_t)a.x; v[1] = (bf16_t)a.y; v[2] = (bf16_t)a.z; v[3] = (bf16_t)a.w;
                    v[4] = (bf16_t)b.x; v[5] = (bf16_t)b.y; v[6] = (bf16_t)b.z; v[7] = (bf16_t)b.w;
                    *(bf16x8*)&As[row * BK + gs * 8] = v;
                }
            }

            // ---- stage qbuf (transposed) ----
            {
                const uint4 w4 = *(const uint4*)(qweight + (size_t)(k0 + qk) * NPK + c0 + qc4);
                qbuf[(qc4 + 0) * SQ + qk] = w4.x;
                qbuf[(qc4 + 1) * SQ + qk] = w4.y;
                qbuf[(qc4 + 2) * SQ + qk] = w4.z;
                qbuf[(qc4 + 3) * SQ + qk] = w4.w;
            }
            __syncthreads();

            // ---- compute: dequant B into registers + MFMA ----
#pragma unroll
            for (int s2 = 0; s2 < 2; ++s2) {
                bf16x8 fa[4], fb[4];
#pragma unroll
                for (int mt = 0; mt < 4; ++mt)
                    fa[mt] = *(const bf16x8*)&As[arowoff[mt] + aslot[s2]];
#pragma unroll
                for (int nt = 0; nt < 4; ++nt) {
                    const uint* qr = &qbuf[qrowoff[nt] + qoff[s2]];
                    const uint4 qa = *(const uint4*)qr;
                    const uint4 qb = *(const uint4*)(qr + 4);
                    bf16x8 v;
                    v[0] = (bf16_t)((float)((qa.x >> jsh) & 15u) * sN[nt] - zsN[nt]);
                    v[1] = (bf16_t)((float)((qa.y >> jsh) & 15u) * sN[nt] - zsN[nt]);
                    v[2] = (bf16_t)((float)((qa.z >> jsh) & 15u) * sN[nt] - zsN[nt]);
                    v[3] = (bf16_t)((float)((qa.w >> jsh) & 15u) * sN[nt] - zsN[nt]);
                    v[4] = (bf16_t)((float)((qb.x >> jsh) & 15u) * sN[nt] - zsN[nt]);
                    v[5] = (bf16_t)((float)((qb.y >> jsh) & 15u) * sN[nt] - zsN[nt]);
                    v[6] = (bf16_t)((float)((qb.z >> jsh) & 15u) * sN[nt] - zsN[nt]);
                    v[7] = (bf16_t)((float)((qb.w >> jsh) & 15u) * sN[nt] - zsN[nt]);
                    fb[nt] = v;
                }
#pragma unroll
                for (int mt = 0; mt < 4; ++mt)
#pragma unroll
                    for (int nt = 0; nt < 4; ++nt)
                        acc[mt][nt] = __builtin_amdgcn_mfma_f32_16x16x32_bf16(fa[mt], fb[nt], acc[mt][nt], 0, 0, 0);
            }
            __syncthreads();
        }
    }

    // ---- epilogue: row=(quad*4+r), col=l16 per 16x16 tile (verified rounds 1-2) ----
#pragma unroll
    for (int nt = 0; nt < 4; ++nt) {
        const int col = n0 + nw + nt * 16 + l16;
        const float b = bias[col];
#pragma unroll
        for (int mt = 0; mt < 4; ++mt) {
#pragma unroll
            for (int r = 0; r < 4; ++r) {
                const int row = m0 + mw + mt * 16 + quad * 4 + r;
                out[(size_t)row * Ndim + col] = acc[mt][nt][r] + b;
            }
        }
    }
}

extern "C" void kernel_launch(void* const* d_in, const int* in_sizes, int n_in,
                              void* d_out, int out_size, void* d_ws, size_t ws_size,
                              hipStream_t stream)
{
    const float* x       = (const float*)d_in[0];
    const uint*  qweight = (const uint*)d_in[1];
    const uint*  qzeros  = (const uint*)d_in[2];
    const float* scales  = (const float*)d_in[3];
    const float* bias    = (const float*)d_in[4];
    float*       out     = (float*)d_out;
    bf16_t*      xb      = (bf16_t*)d_ws;

    const size_t xb_bytes = (size_t)Mdim * Kdim * sizeof(bf16_t);
    dim3 grid(Ndim / BN, Mdim / BM);   // 86 x 16 = 1376 blocks

    if (ws_size >= xb_bytes) {
        xcast_kernel<<<(Mdim * Kdim) / (256 * 8), 256, 0, stream>>>(x, xb);
        qgemm_kernel<true><<<grid, dim3(256), 0, stream>>>(x, xb, qweight, qzeros, scales, bias, out);
    } else {
        qgemm_kernel<false><<<grid, dim3(256), 0, stream>>>(x, xb, qweight, qzeros, scales, bias, out);
    }
}

// Round 4
// 404.370 us; speedup vs baseline: 1.1017x; 1.1017x over previous
//
#include <hip/hip_runtime.h>

typedef _Float16 half_t;
typedef half_t halfx2 __attribute__((ext_vector_type(2)));
typedef half_t halfx8 __attribute__((ext_vector_type(8)));
typedef float  floatx4 __attribute__((ext_vector_type(4)));
typedef unsigned int uint;

constexpr int Mdim = 2048;
constexpr int Kdim = 4096;
constexpr int Ndim = 11008;
constexpr int NPK  = Ndim / 8;     // 1376 packed words per k-row
constexpr int BM = 128, BN = 128, BK = 64;
constexpr int SQ = 68;             // qbuf stride in words (bank-staggered, 16B-aligned)

__global__ void xcast_kernel(const float* __restrict__ x, half_t* __restrict__ xh)
{
    const int i = (blockIdx.x * 256 + threadIdx.x) * 8;
    const float4 a = *(const float4*)(x + i);
    const float4 b = *(const float4*)(x + i + 4);
    halfx8 v;
    v[0] = (half_t)a.x; v[1] = (half_t)a.y; v[2] = (half_t)a.z; v[3] = (half_t)a.w;
    v[4] = (half_t)b.x; v[5] = (half_t)b.y; v[6] = (half_t)b.z; v[7] = (half_t)b.w;
    *(halfx8*)(xh + i) = v;
}

__device__ __forceinline__ void gload_lds16(const half_t* g, half_t* l)
{
    __builtin_amdgcn_global_load_lds((const __attribute__((address_space(1))) void*)g,
                                     (__attribute__((address_space(3))) void*)l, 16, 0, 0);
}

__device__ __forceinline__ halfx2 dq2(uint q0, uint q1, int jsh, halfx2 s2, halfx2 c2)
{
    // fp16(16+v) = 0x4C00 | (v<<6), exact for v in [0,15]
    const uint w = 0x4C004C00u | (((q0 >> jsh) & 15u) << 6) | (((q1 >> jsh) & 15u) << 22);
    const halfx2 h = __builtin_bit_cast(halfx2, w);
    return h * s2 + c2;    // pk_fma: (16+v)*s - (16+z)*s = (v-z)*s
}

template <bool PRE>
__global__ __launch_bounds__(256, 4)
void qgemm_kernel(const float* __restrict__ x,
                  const half_t* __restrict__ xh,
                  const uint* __restrict__ qweight,
                  const uint* __restrict__ qzeros,
                  const float* __restrict__ scales,
                  const float* __restrict__ bias,
                  float* __restrict__ out)
{
    // As/Bs: 128 rows x 64 halves, UNPADDED (128 B row), 16B-granule XOR swizzle:
    // LDS slot (row, g) holds logical granule g ^ (row&7).
    __shared__ half_t As[BM * BK];     // 16384 B  [m][k]
    __shared__ half_t Bs[BN * BK];     // 16384 B  [n][k]
    __shared__ uint   qbuf[16 * SQ];   //  4352 B  [c][k] transposed packed words

    const int t  = threadIdx.x;
    const int m0 = blockIdx.x * BM;    // m-fastest: adjacent blocks share qweight n-slice
    const int n0 = blockIdx.y * BN;
    const int c0 = n0 >> 3;

    const int wave = t >> 6;
    const int lane = t & 63;
    const int quad = lane >> 4;
    const int l16  = lane & 15;
    const int mw = (wave >> 1) * 64;
    const int nw = (wave & 1) * 64;

    // A staging (global_load_lds): lane -> row wave*8 + (lane>>3), slot gs=lane&7,
    // fetch global granule gs ^ (row&7).
    const int r8   = lane >> 3;
    const int gs   = lane & 7;
    const int gcol = gs ^ r8;

    // qbuf staging: thread loads dwordx4 at (k0+qk, c0+qc4..+3), stores transposed
    const int qk  = t >> 2;
    const int qc4 = (t & 3) * 4;

    // dequant-once: thread owns column nloc, k-range [khalf*32, +32)
    const int nloc   = t & 127;
    const int khalf  = t >> 7;
    const int cc     = nloc >> 3;
    const int jshq   = (nloc & 7) * 4;
    const int nsw    = nloc & 7;       // swizzle key for Bs writes

    // fragment read offsets
    const int e3 = l16 & 7;
    int arow[4], brow[4];
#pragma unroll
    for (int mt = 0; mt < 4; ++mt) arow[mt] = (mw + mt * 16 + l16) * BK;
#pragma unroll
    for (int nt = 0; nt < 4; ++nt) brow[nt] = (nw + nt * 16 + l16) * BK;
    int aslot[2];
#pragma unroll
    for (int s2i = 0; s2i < 2; ++s2i)
        aslot[s2i] = ((s2i * 4 + quad) ^ e3) * 8;

    floatx4 acc[4][4];
#pragma unroll
    for (int i = 0; i < 4; ++i)
#pragma unroll
        for (int j = 0; j < 4; ++j)
            acc[i][j] = (floatx4){0.f, 0.f, 0.f, 0.f};

    for (int g = 0; g < 32; ++g) {
        // per-group dequant constants (1 scale + 1 zeros word per thread)
        const float sv = scales[(size_t)g * Ndim + n0 + nloc];
        const uint  zw = qzeros[(size_t)g * NPK + c0 + cc];
        const float zf = (float)((zw >> jshq) & 15u);
        halfx2 s2, c2;
        s2[0] = (half_t)sv;                  s2[1] = s2[0];
        c2[0] = (half_t)(-(16.0f + zf) * sv); c2[1] = c2[0];

#pragma unroll 1
        for (int half = 0; half < 2; ++half) {
            const int k0 = g * 128 + half * 64;

            // ---- stage A ----
            if (PRE) {
#pragma unroll
                for (int p = 0; p < 4; ++p) {
                    const half_t* gp = xh + (size_t)(m0 + p * 32 + wave * 8 + r8) * Kdim
                                          + k0 + gcol * 8;
                    gload_lds16(gp, &As[(p * 32 + wave * 8) * BK]);
                }
            } else {
#pragma unroll
                for (int p = 0; p < 4; ++p) {
                    const int row = p * 32 + wave * 8 + r8;
                    const float* src = x + (size_t)(m0 + row) * Kdim + k0 + gcol * 8;
                    const float4 a = *(const float4*)src;
                    const float4 b = *(const float4*)(src + 4);
                    halfx8 v;
                    v[0] = (half_t)a.x; v[1] = (half_t)a.y; v[2] = (half_t)a.z; v[3] = (half_t)a.w;
                    v[4] = (half_t)b.x; v[5] = (half_t)b.y; v[6] = (half_t)b.z; v[7] = (half_t)b.w;
                    *(halfx8*)&As[row * BK + gs * 8] = v;
                }
            }

            // ---- stage qbuf (transposed) ----
            {
                const uint4 w4 = *(const uint4*)(qweight + (size_t)(k0 + qk) * NPK + c0 + qc4);
                qbuf[(qc4 + 0) * SQ + qk] = w4.x;
                qbuf[(qc4 + 1) * SQ + qk] = w4.y;
                qbuf[(qc4 + 2) * SQ + qk] = w4.z;
                qbuf[(qc4 + 3) * SQ + qk] = w4.w;
            }
            __syncthreads();

            // ---- dequant-once -> Bs (swizzled b128 writes) ----
            {
                const uint* qrow = &qbuf[cc * SQ + khalf * 32];
#pragma unroll
                for (int j = 0; j < 4; ++j) {
                    const uint4 qa = *(const uint4*)(qrow + j * 8);      // broadcast reads
                    const uint4 qb = *(const uint4*)(qrow + j * 8 + 4);
                    halfx8 v;
                    halfx2 p;
                    p = dq2(qa.x, qa.y, jshq, s2, c2); v[0] = p[0]; v[1] = p[1];
                    p = dq2(qa.z, qa.w, jshq, s2, c2); v[2] = p[0]; v[3] = p[1];
                    p = dq2(qb.x, qb.y, jshq, s2, c2); v[4] = p[0]; v[5] = p[1];
                    p = dq2(qb.z, qb.w, jshq, s2, c2); v[6] = p[0]; v[7] = p[1];
                    const int slot = (khalf * 4 + j) ^ nsw;
                    *(halfx8*)&Bs[nloc * BK + slot * 8] = v;
                }
            }
            __syncthreads();

            // ---- MFMA: 2 k-steps of 32 ----
#pragma unroll
            for (int s2i = 0; s2i < 2; ++s2i) {
                halfx8 fa[4], fb[4];
#pragma unroll
                for (int mt = 0; mt < 4; ++mt)
                    fa[mt] = *(const halfx8*)&As[arow[mt] + aslot[s2i]];
#pragma unroll
                for (int nt = 0; nt < 4; ++nt)
                    fb[nt] = *(const halfx8*)&Bs[brow[nt] + aslot[s2i]];
#pragma unroll
                for (int mt = 0; mt < 4; ++mt)
#pragma unroll
                    for (int nt = 0; nt < 4; ++nt)
                        acc[mt][nt] = __builtin_amdgcn_mfma_f32_16x16x32_f16(fa[mt], fb[nt], acc[mt][nt], 0, 0, 0);
            }
            __syncthreads();
        }
    }

    // ---- epilogue: row=(quad*4+r), col=l16 per 16x16 tile (verified rounds 1-3) ----
#pragma unroll
    for (int nt = 0; nt < 4; ++nt) {
        const int col = n0 + nw + nt * 16 + l16;
        const float b = bias[col];
#pragma unroll
        for (int mt = 0; mt < 4; ++mt) {
#pragma unroll
            for (int r = 0; r < 4; ++r) {
                const int row = m0 + mw + mt * 16 + quad * 4 + r;
                out[(size_t)row * Ndim + col] = acc[mt][nt][r] + b;
            }
        }
    }
}

extern "C" void kernel_launch(void* const* d_in, const int* in_sizes, int n_in,
                              void* d_out, int out_size, void* d_ws, size_t ws_size,
                              hipStream_t stream)
{
    const float* x       = (const float*)d_in[0];
    const uint*  qweight = (const uint*)d_in[1];
    const uint*  qzeros  = (const uint*)d_in[2];
    const float* scales  = (const float*)d_in[3];
    const float* bias    = (const float*)d_in[4];
    float*       out     = (float*)d_out;
    half_t*      xh      = (half_t*)d_ws;

    const size_t xh_bytes = (size_t)Mdim * Kdim * sizeof(half_t);
    dim3 grid(Mdim / BM, Ndim / BN);   // m-fastest: 16 x 86

    if (ws_size >= xh_bytes) {
        xcast_kernel<<<(Mdim * Kdim) / (256 * 8), 256, 0, stream>>>(x, xh);
        qgemm_kernel<true><<<grid, dim3(256), 0, stream>>>(x, xh, qweight, qzeros, scales, bias, out);
    } else {
        qgemm_kernel<false><<<grid, dim3(256), 0, stream>>>(x, xh, qweight, qzeros, scales, bias, out);
    }
}